// Round 7
// baseline (46.389 us; speedup 1.0000x reference)
//
#include <hip/hip_runtime.h>

#define N_TIME  112
#define BATCH   262144
#define NF4ROW  28      // float4 per row
#define NCH     7       // chunks of 16 cols (4 float4) per row

typedef float vfloat4 __attribute__((ext_vector_type(4)));

__device__ __forceinline__ float sig(float cap, float c, float vp,
                                     float kd, float invT10) {
    const float TR     = 0.005f;
    const float R1     = 4.5f;
    const float SINA20 = 20.0f * 0.25881904510252074f;  // 20*sin(15deg)
    const float COSA   = 0.96592582628906829f;          // cos(15deg)
    float ct = vp * cap + kd * c;
    float e  = __expf(-TR * (invT10 + R1 * ct));
    return (1.0f - e) * SINA20 * __builtin_amdgcn_rcpf(1.0f - e * COSA);
}

__global__ __launch_bounds__(256) void etofts_kernel(
    const float* __restrict__ ktrans_p,
    const float* __restrict__ vp_p,
    const float* __restrict__ ve_p,
    const float* __restrict__ T10_p,
    const float* __restrict__ cap_p,
    float* __restrict__ out_p)
{
    const int tid = blockIdx.x * blockDim.x + threadIdx.x;
    const int row = tid >> 2;          // 4 threads per row
    const int t   = tid & 3;           // sub-lane within row

    const float DELTT  = 4.0f / 60.0f;
    const float ktrans = ktrans_p[row];
    const float vp     = vp_p[row];
    const float ve     = ve_p[row];
    const float invT10 = __builtin_amdgcn_rcpf(T10_p[row]);
    const float kd     = ktrans * DELTT;

    const float d1  = __expf(-ktrans / ve * DELTT);   // decay
    const float d2  = d1 * d1;
    const float d3  = d2 * d1;
    const float d4  = d2 * d2;
    const float d8  = d4 * d4;
    const float d12 = d8 * d4;
    const float d16 = d8 * d8;
    const float dt4 = (t == 0) ? 1.0f : (t == 1) ? d4 : (t == 2) ? d8 : d12;

    // Lane's float4 for chunk ch lives at row*28 + ch*4 + t  (full 64B lines
    // per 4-lane group; every load/store instruction covers 16 whole lines).
    const float4* capv = reinterpret_cast<const float4*>(cap_p) + (size_t)row * NF4ROW + t;
    vfloat4*      outv = reinterpret_cast<vfloat4*>(out_p)      + (size_t)row * NF4ROW + t;

    float c_in = 0.0f;   // IIR state entering current chunk

    // Rolling depth-2 prefetch; no LDS, no barriers -> loads stay in flight.
    float4 xa = capv[0];
    float4 xb = capv[4];

    #pragma unroll
    for (int ch = 0; ch < NCH; ++ch) {
        float4 xf;
        if (ch + 2 < NCH) xf = capv[(ch + 2) * 4];

        const float4 x = xa;

        // Local 4-element scan (zero init).
        float s0 = x.x;
        float s1 = fmaf(d1, s0, x.y);
        float s2 = fmaf(d1, s1, x.z);
        float s3 = fmaf(d1, s2, x.w);

        // Inclusive scan of s3 across the 4-lane group, ratio d4.
        float S  = s3;
        float v1 = __shfl_up(S, 1, 4);
        if (t >= 1) S = fmaf(d4, v1, S);
        float v2 = __shfl_up(S, 2, 4);
        if (t >= 2) S = fmaf(d8, v2, S);

        // Exclusive lane prefix + carry from previous chunk.
        float E   = __shfl_up(S, 1, 4);                 // S_{t-1} (valid t>=1)
        float tin = (t == 0) ? dt4 * c_in : fmaf(dt4, c_in, E);

        // Next chunk's carry = value at this chunk's last col (lane 3's S).
        float S3 = __shfl(S, 3, 4);
        c_in = fmaf(d16, c_in, S3);

        // Final scan values for this lane's 4 columns.
        float c0 = fmaf(d1, tin, s0);
        float c1 = fmaf(d2, tin, s1);
        float c2 = fmaf(d3, tin, s2);
        float c3 = fmaf(d4, tin, s3);

        vfloat4 y;
        y.x = sig(x.x, c0, vp, kd, invT10);
        y.y = sig(x.y, c1, vp, kd, invT10);
        y.z = sig(x.z, c2, vp, kd, invT10);
        y.w = sig(x.w, c3, vp, kd, invT10);

        // Non-temporal store: output is write-once, never read -> don't let it
        // evict CAp from L2/L3 (keep the input Infinity-Cache-resident).
        __builtin_nontemporal_store(y, &outv[ch * 4]);

        xa = xb;
        xb = xf;
    }
}

extern "C" void kernel_launch(void* const* d_in, const int* in_sizes, int n_in,
                              void* d_out, int out_size, void* d_ws, size_t ws_size,
                              hipStream_t stream) {
    const float* ktrans = (const float*)d_in[0];
    const float* vp     = (const float*)d_in[1];
    const float* ve     = (const float*)d_in[2];
    const float* T10    = (const float*)d_in[3];
    const float* CAp    = (const float*)d_in[4];
    float* out = (float*)d_out;

    dim3 block(256);
    dim3 grid((BATCH * 4) / 256);   // 4 threads per row
    etofts_kernel<<<grid, block, 0, stream>>>(ktrans, vp, ve, T10, CAp, out);
}

// Round 8
// 43.877 us; speedup vs baseline: 1.0573x; 1.0573x over previous
//
#include <hip/hip_runtime.h>

#define N_TIME  112
#define BATCH   262144
#define NF4ROW  28      // float4 per row
#define NCH     7       // chunks of 16 cols (4 float4) per row

__device__ __forceinline__ float sig(float cap, float c, float vp,
                                     float kd, float invT10) {
    const float TR     = 0.005f;
    const float R1     = 4.5f;
    const float SINA20 = 20.0f * 0.25881904510252074f;  // 20*sin(15deg)
    const float COSA   = 0.96592582628906829f;          // cos(15deg)
    float ct = vp * cap + kd * c;
    float e  = __expf(-TR * (invT10 + R1 * ct));
    return (1.0f - e) * SINA20 * __builtin_amdgcn_rcpf(1.0f - e * COSA);
}

__global__ __launch_bounds__(256) void etofts_kernel(
    const float* __restrict__ ktrans_p,
    const float* __restrict__ vp_p,
    const float* __restrict__ ve_p,
    const float* __restrict__ T10_p,
    const float* __restrict__ cap_p,
    float* __restrict__ out_p)
{
    const int tid = blockIdx.x * blockDim.x + threadIdx.x;
    const int row = tid >> 2;          // 4 threads per row
    const int t   = tid & 3;           // sub-lane within row

    const float DELTT  = 4.0f / 60.0f;
    const float ktrans = ktrans_p[row];
    const float vp     = vp_p[row];
    const float ve     = ve_p[row];
    const float invT10 = __builtin_amdgcn_rcpf(T10_p[row]);
    const float kd     = ktrans * DELTT;

    const float d1  = __expf(-ktrans / ve * DELTT);   // decay
    const float d2  = d1 * d1;
    const float d3  = d2 * d1;
    const float d4  = d2 * d2;
    const float d8  = d4 * d4;
    const float d12 = d8 * d4;
    const float d16 = d8 * d8;
    const float dt4 = (t == 0) ? 1.0f : (t == 1) ? d4 : (t == 2) ? d8 : d12;

    const float4* capv = reinterpret_cast<const float4*>(cap_p) + (size_t)row * NF4ROW + t;
    float4*       outv = reinterpret_cast<float4*>(out_p)       + (size_t)row * NF4ROW + t;

    // ---- Phase 0: issue ALL chunk loads up front (7 in flight, no barriers).
    float4 x[NCH];
    #pragma unroll
    for (int ch = 0; ch < NCH; ++ch) x[ch] = capv[ch * 4];

    // ---- Phase 1: local 4-scans + cross-lane 4-scans, ALL chunks independent
    // (shuffle latencies overlap across chunks; serial depth = 3 shuffles).
    float s1[NCH], s2[NCH], s3[NCH], E[NCH], T[NCH];
    #pragma unroll
    for (int ch = 0; ch < NCH; ++ch) {
        float a0 = x[ch].x;
        float a1 = fmaf(d1, a0, x[ch].y);
        float a2 = fmaf(d1, a1, x[ch].z);
        float a3 = fmaf(d1, a2, x[ch].w);
        s1[ch] = a1; s2[ch] = a2; s3[ch] = a3;

        float S  = a3;
        float v1 = __shfl_up(S, 1, 4);
        if (t >= 1) S = fmaf(d4, v1, S);
        float v2 = __shfl_up(S, 2, 4);
        if (t >= 2) S = fmaf(d8, v2, S);

        E[ch] = __shfl_up(S, 1, 4);   // exclusive lane prefix (valid t>=1)
        T[ch] = __shfl(S, 3, 4);      // chunk total (broadcast)
    }

    // ---- Phase 2: the ONLY serial part — 7 dependent FMAs for chunk carries.
    float C[NCH];
    C[0] = 0.0f;
    #pragma unroll
    for (int ch = 0; ch < NCH - 1; ++ch) C[ch + 1] = fmaf(d16, C[ch], T[ch]);

    // ---- Phase 3: independent per-chunk epilogue + coalesced stores.
    #pragma unroll
    for (int ch = 0; ch < NCH; ++ch) {
        float tin = (t == 0) ? dt4 * C[ch] : fmaf(dt4, C[ch], E[ch]);

        float c0 = fmaf(d1, tin, x[ch].x);
        float c1 = fmaf(d2, tin, s1[ch]);
        float c2 = fmaf(d3, tin, s2[ch]);
        float c3 = fmaf(d4, tin, s3[ch]);

        float4 y;
        y.x = sig(x[ch].x, c0, vp, kd, invT10);
        y.y = sig(x[ch].y, c1, vp, kd, invT10);
        y.z = sig(x[ch].z, c2, vp, kd, invT10);
        y.w = sig(x[ch].w, c3, vp, kd, invT10);
        outv[ch * 4] = y;
    }
}

extern "C" void kernel_launch(void* const* d_in, const int* in_sizes, int n_in,
                              void* d_out, int out_size, void* d_ws, size_t ws_size,
                              hipStream_t stream) {
    const float* ktrans = (const float*)d_in[0];
    const float* vp     = (const float*)d_in[1];
    const float* ve     = (const float*)d_in[2];
    const float* T10    = (const float*)d_in[3];
    const float* CAp    = (const float*)d_in[4];
    float* out = (float*)d_out;

    dim3 block(256);
    dim3 grid((BATCH * 4) / 256);   // 4 threads per row
    etofts_kernel<<<grid, block, 0, stream>>>(ktrans, vp, ve, T10, CAp, out);
}

// Round 9
// 40.796 us; speedup vs baseline: 1.1371x; 1.0755x over previous
//
#include <hip/hip_runtime.h>

#define N_TIME  112
#define BATCH   262144
#define NF4ROW  28      // float4 per row
#define NCH     7       // chunks of 16 cols (4 float4) per row
#define RPW     16      // rows per wave
#define LP      29      // LDS row pitch in float4 (padded, bank-balanced)

__device__ __forceinline__ float sig(float cap, float c, float vp,
                                     float kd, float invT10) {
    const float TR     = 0.005f;
    const float R1     = 4.5f;
    const float SINA20 = 20.0f * 0.25881904510252074f;  // 20*sin(15deg)
    const float COSA   = 0.96592582628906829f;          // cos(15deg)
    float ct = vp * cap + kd * c;
    float e  = __expf(-TR * (invT10 + R1 * ct));
    return (1.0f - e) * SINA20 * __builtin_amdgcn_rcpf(1.0f - e * COSA);
}

__global__ __launch_bounds__(256) void etofts_kernel(
    const float* __restrict__ ktrans_p,
    const float* __restrict__ vp_p,
    const float* __restrict__ ve_p,
    const float* __restrict__ T10_p,
    const float* __restrict__ cap_p,
    float* __restrict__ out_p)
{
    // Wave-private tiles (16 rows x 29 float4 = 7424 B each); NO __syncthreads
    // anywhere -> no vmcnt(0) drains, loads stay in flight across phases.
    __shared__ float4 tile[4][RPW * LP];   // 29696 B / block

    const int w    = threadIdx.x >> 6;
    const int lane = threadIdx.x & 63;
    const int g0   = blockIdx.x * 64 + w * RPW;   // wave's first row

    float4* wt = tile[w];

    // Wave's flat global window: 16 rows x 28 float4 = 448 float4 = 7 KB.
    const float4* src = reinterpret_cast<const float4*>(cap_p) + (size_t)g0 * NF4ROW;
    float4*       dst = reinterpret_cast<float4*>(out_p)       + (size_t)g0 * NF4ROW;

    // ---- Flat cooperative loads: each instruction = 64 lanes x 16 B = 1 KB
    // CONTIGUOUS (DRAM row-buffer friendly), 7 in flight.
    float4 ld[NCH];
    int    slot[NCH];
    #pragma unroll
    for (int k = 0; k < NCH; ++k) {
        int f   = lane + (k << 6);            // 0..447
        ld[k]   = src[f];
        slot[k] = (f / NF4ROW) * LP + (f % NF4ROW);
    }

    // Per-row parameters (4 lanes per row share -> broadcast loads).
    const int r    = lane >> 2;               // row within wave
    const int t    = lane & 3;                // sub-lane within row
    const int grow = g0 + r;

    const float DELTT  = 4.0f / 60.0f;
    const float ktrans = ktrans_p[grow];
    const float vp     = vp_p[grow];
    const float ve     = ve_p[grow];
    const float invT10 = __builtin_amdgcn_rcpf(T10_p[grow]);
    const float kd     = ktrans * DELTT;

    const float d1  = __expf(-ktrans / ve * DELTT);
    const float d2  = d1 * d1;
    const float d3  = d2 * d1;
    const float d4  = d2 * d2;
    const float d8  = d4 * d4;
    const float d12 = d8 * d4;
    const float d16 = d8 * d8;
    const float dt4 = (t == 0) ? 1.0f : (t == 1) ? d4 : (t == 2) ? d8 : d12;

    // ---- Transpose in: flat -> row-major tile (wave-private, no barrier).
    #pragma unroll
    for (int k = 0; k < NCH; ++k) wt[slot[k]] = ld[k];

    // ---- Gather this lane's row-chunks from LDS.
    float4 x[NCH];
    #pragma unroll
    for (int ch = 0; ch < NCH; ++ch) x[ch] = wt[r * LP + ch * 4 + t];

    // ---- Parallel local + cross-lane scans (all chunks independent).
    float s1[NCH], s2[NCH], s3[NCH], E[NCH], T[NCH];
    #pragma unroll
    for (int ch = 0; ch < NCH; ++ch) {
        float a0 = x[ch].x;
        float a1 = fmaf(d1, a0, x[ch].y);
        float a2 = fmaf(d1, a1, x[ch].z);
        float a3 = fmaf(d1, a2, x[ch].w);
        s1[ch] = a1; s2[ch] = a2; s3[ch] = a3;

        float S  = a3;
        float v1 = __shfl_up(S, 1, 4);
        if (t >= 1) S = fmaf(d4, v1, S);
        float v2 = __shfl_up(S, 2, 4);
        if (t >= 2) S = fmaf(d8, v2, S);

        E[ch] = __shfl_up(S, 1, 4);   // exclusive lane prefix (valid t>=1)
        T[ch] = __shfl(S, 3, 4);      // chunk total (broadcast)
    }

    // ---- Serial part: 7 dependent FMAs for chunk carries.
    float C[NCH];
    C[0] = 0.0f;
    #pragma unroll
    for (int ch = 0; ch < NCH - 1; ++ch) C[ch + 1] = fmaf(d16, C[ch], T[ch]);

    // ---- Epilogue per chunk; results back into the tile (in place).
    #pragma unroll
    for (int ch = 0; ch < NCH; ++ch) {
        float tin = (t == 0) ? dt4 * C[ch] : fmaf(dt4, C[ch], E[ch]);

        float c0 = fmaf(d1, tin, x[ch].x);
        float c1 = fmaf(d2, tin, s1[ch]);
        float c2 = fmaf(d3, tin, s2[ch]);
        float c3 = fmaf(d4, tin, s3[ch]);

        float4 y;
        y.x = sig(x[ch].x, c0, vp, kd, invT10);
        y.y = sig(x[ch].y, c1, vp, kd, invT10);
        y.z = sig(x[ch].z, c2, vp, kd, invT10);
        y.w = sig(x[ch].w, c3, vp, kd, invT10);
        wt[r * LP + ch * 4 + t] = y;
    }

    // ---- Transpose out: tile -> flat, 7 contiguous 1 KB stores per wave.
    #pragma unroll
    for (int k = 0; k < NCH; ++k) dst[lane + (k << 6)] = wt[slot[k]];
}

extern "C" void kernel_launch(void* const* d_in, const int* in_sizes, int n_in,
                              void* d_out, int out_size, void* d_ws, size_t ws_size,
                              hipStream_t stream) {
    const float* ktrans = (const float*)d_in[0];
    const float* vp     = (const float*)d_in[1];
    const float* ve     = (const float*)d_in[2];
    const float* T10    = (const float*)d_in[3];
    const float* CAp    = (const float*)d_in[4];
    float* out = (float*)d_out;

    dim3 block(256);
    dim3 grid(BATCH / 64);   // 64 rows per block (16 per wave)
    etofts_kernel<<<grid, block, 0, stream>>>(ktrans, vp, ve, T10, CAp, out);
}